// Round 8
// baseline (296.611 us; speedup 1.0000x reference)
//
#include <hip/hip_runtime.h>

#define DD 128

typedef __attribute__((ext_vector_type(8))) short bf16x8;
typedef __attribute__((ext_vector_type(4))) float f32x4;

__device__ __forceinline__ float b2f(unsigned short u) {
    return __uint_as_float(((unsigned)u) << 16);
}
__device__ __forceinline__ unsigned short f2b(float f) {
    unsigned u = __float_as_uint(f);
    unsigned r = (u + 0x7FFFu + ((u >> 16) & 1u)) >> 16;
    return (unsigned short)r;
}

// ---------------- CSR build ----------------

__global__ __launch_bounds__(256) void hist_kernel(const int* __restrict__ ei,
                                                   int* __restrict__ cnt, int E) {
    int e = blockIdx.x * 256 + threadIdx.x;
    if (e < E) atomicAdd(&cnt[ei[E + e]], 1);   // dst = edge_index[1][e]
}

__global__ __launch_bounds__(256) void scan1_kernel(const int* __restrict__ cnt,
                                                    int* __restrict__ startv,
                                                    int* __restrict__ bsum, int n) {
    int i = blockIdx.x * 256 + threadIdx.x;
    int v = (i < n) ? cnt[i] : 0;
    int lane = threadIdx.x & 63, wid = threadIdx.x >> 6;
    int incl = v;
#pragma unroll
    for (int o = 1; o < 64; o <<= 1) {
        int t = __shfl_up(incl, o);
        if (lane >= o) incl += t;
    }
    __shared__ int wsum[4];
    __shared__ int wpre[4];
    if (lane == 63) wsum[wid] = incl;
    __syncthreads();
    if (threadIdx.x == 0) {
        int s = 0;
        for (int w2 = 0; w2 < 4; ++w2) { wpre[w2] = s; s += wsum[w2]; }
        bsum[blockIdx.x] = s;
    }
    __syncthreads();
    if (i < n) startv[i] = incl - v + wpre[wid];
}

__global__ __launch_bounds__(512) void scan2_kernel(int* bsum, int nb) {
    int i = threadIdx.x;
    int v = (i < nb) ? bsum[i] : 0;
    int lane = threadIdx.x & 63, wid = threadIdx.x >> 6;
    int incl = v;
#pragma unroll
    for (int o = 1; o < 64; o <<= 1) {
        int t = __shfl_up(incl, o);
        if (lane >= o) incl += t;
    }
    __shared__ int wsum[8];
    __shared__ int wpre[8];
    if (lane == 63) wsum[wid] = incl;
    __syncthreads();
    if (threadIdx.x == 0) {
        int s = 0;
        for (int w2 = 0; w2 < 8; ++w2) { wpre[w2] = s; s += wsum[w2]; }
    }
    __syncthreads();
    if (i < nb) bsum[i] = incl - v + wpre[wid];
}

__global__ __launch_bounds__(256) void scan3_kernel(int* startv, int* cursor,
                                                    const int* __restrict__ bsum,
                                                    int n, int E) {
    int i = blockIdx.x * 256 + threadIdx.x;
    if (i < n) {
        int s = startv[i] + bsum[i >> 8];
        startv[i] = s;
        cursor[i] = s;
    } else if (i == n) {
        startv[n] = E;
    }
}

// ---------------- fused fill (CSR scatter) + conversions ----------------
// blocks [0,ebl): fill ; [ebl,+bx): x0->xb ; [+br): r0->r0b ; [+384): 6 W transposes.

__global__ __launch_bounds__(256) void fill_conv_kernel(
    const int* __restrict__ ei, const int* __restrict__ ety,
    const float* __restrict__ ew, int* cursor, uint2* __restrict__ csre, int E, int ebl,
    const float* __restrict__ x0, unsigned short* __restrict__ xb, int bx, int n4x,
    const float* __restrict__ r0, unsigned short* __restrict__ r0b, int br, int n4r,
    const float* __restrict__ W0, const float* __restrict__ Ws0,
    const float* __restrict__ W1, const float* __restrict__ Ws1,
    const float* __restrict__ Wr0, const float* __restrict__ Wr1,
    unsigned short* __restrict__ wt0a, unsigned short* __restrict__ wt0s,
    unsigned short* __restrict__ wt1a, unsigned short* __restrict__ wt1s,
    unsigned short* __restrict__ wtr0, unsigned short* __restrict__ wtr1) {
    int bid = blockIdx.x;
    if (bid < ebl) {
        int e = bid * 256 + threadIdx.x;
        if (e < E) {
            int dst = ei[E + e];
            int p = atomicAdd(&cursor[dst], 1);
            uint2 rec;
            rec.x = ((unsigned)ei[e]) | (((unsigned)ety[e]) << 20);  // src | (rel<<20)
            rec.y = __float_as_uint(ew[e]);
            __builtin_nontemporal_store(*(unsigned long long*)&rec,
                                        (unsigned long long*)&csre[p]);
        }
        return;
    }
    bid -= ebl;
    if (bid < bx) {
        int i = bid * 256 + threadIdx.x;
        if (i < n4x) {
            float4 v = ((const float4*)x0)[i];
            ((ushort4*)xb)[i] = make_ushort4(f2b(v.x), f2b(v.y), f2b(v.z), f2b(v.w));
        }
        return;
    }
    bid -= bx;
    if (bid < br) {
        int i = bid * 256 + threadIdx.x;
        if (i < n4r) {
            float4 v = ((const float4*)r0)[i];
            ((ushort4*)r0b)[i] = make_ushort4(f2b(v.x), f2b(v.y), f2b(v.z), f2b(v.w));
        }
        return;
    }
    bid -= br;
    int which = bid >> 6;
    int i = (bid & 63) * 256 + threadIdx.x;  // 0..16383
    int cc = i >> 7, k = i & 127;
    const float* Wsel = which == 0 ? W0 : which == 1 ? Ws0 : which == 2 ? W1
                      : which == 3 ? Ws1 : which == 4 ? Wr0 : Wr1;
    unsigned short* Osel = which == 0 ? wt0a : which == 1 ? wt0s : which == 2 ? wt1a
                         : which == 3 ? wt1s : which == 4 ? wtr0 : wtr1;
    Osel[i] = f2b(Wsel[k * DD + cc]);        // Wt[c][k] = W[k][c]
}

// ---------------- fused layer: aggregate + dual GEMM (nodes) / GEMM (rel) ----------
// node blocks [0,nblk): 128 rows. agg: 4 lanes/node, 2-edge unroll, rel from L2.
// agg tile dumped bf16 XOR-swizzled into 32KB LDS; gemm reads A from LDS,
// X(self) and weights from global (L1/L2-resident).
// rel blocks [nblk, nblk+rblk): stage rel rows into LDS, single-W GEMM.

__global__ __launch_bounds__(512, 4) void fused_layer_kernel(
    const unsigned short* __restrict__ gx,      // bf16 [N,128] gather+self input
    const unsigned short* __restrict__ relb,    // bf16 [R,128] rel table
    const unsigned short* __restrict__ wtA, const unsigned short* __restrict__ wtX,
    const unsigned short* __restrict__ wtR,     // transposed bf16 [c][k]
    const int* __restrict__ startv, const uint2* __restrict__ csre,
    float* __restrict__ outf, unsigned short* __restrict__ outb,
    float* __restrict__ reloutf, unsigned short* __restrict__ reloutb,
    int N, int R, int relu, int nblk)
{
    __shared__ unsigned short sA[DD * DD];      // 32 KB: bf16 A-tile, XOR-swizzled
    int tid = threadIdx.x;
    bool isrel = (int)blockIdx.x >= nblk;

    if (!isrel) {
        // ---- phase 1: aggregate 128 nodes, 4 lanes/node (32 f32 each) ----
        int nl = tid >> 2, c = tid & 3;         // node-local, chunk quarter
        int gnode = blockIdx.x * DD + nl;
        int i0 = 0, e0 = 0;
        if (gnode < N) { i0 = startv[gnode]; e0 = startv[gnode + 1]; }
        const bf16x8* X8 = (const bf16x8*)gx;
        const bf16x8* R8 = (const bf16x8*)relb;
        float a[32];
#pragma unroll
        for (int j = 0; j < 32; ++j) a[j] = 0.f;
        for (int i = i0; i < e0; i += 2) {
            bool v1 = i + 1 < e0;
            uint2 cc0 = csre[i];
            uint2 cc1 = csre[v1 ? i + 1 : 0];
            float w0 = __uint_as_float(cc0.y);
            float w1 = v1 ? __uint_as_float(cc1.y) : 0.f;
            size_t s0 = (size_t)(cc0.x & 0xFFFFFu) * 16 + c * 4;
            size_t s1 = (size_t)(cc1.x & 0xFFFFFu) * 16 + c * 4;
            int t0 = (int)(cc0.x >> 20) * 16 + c * 4;
            int t1 = (int)(cc1.x >> 20) * 16 + c * 4;
            bf16x8 xa0 = X8[s0 + 0], xa1 = X8[s0 + 1], xa2 = X8[s0 + 2], xa3 = X8[s0 + 3];
            bf16x8 ra0 = R8[t0 + 0], ra1 = R8[t0 + 1], ra2 = R8[t0 + 2], ra3 = R8[t0 + 3];
            bf16x8 xb0 = X8[s1 + 0], xb1 = X8[s1 + 1], xb2 = X8[s1 + 2], xb3 = X8[s1 + 3];
            bf16x8 rb0 = R8[t1 + 0], rb1 = R8[t1 + 1], rb2 = R8[t1 + 2], rb3 = R8[t1 + 3];
#pragma unroll
            for (int q = 0; q < 8; ++q) {
                a[q]      += (b2f((unsigned short)xa0[q]) - b2f((unsigned short)ra0[q])) * w0
                           + (b2f((unsigned short)xb0[q]) - b2f((unsigned short)rb0[q])) * w1;
                a[8 + q]  += (b2f((unsigned short)xa1[q]) - b2f((unsigned short)ra1[q])) * w0
                           + (b2f((unsigned short)xb1[q]) - b2f((unsigned short)rb1[q])) * w1;
                a[16 + q] += (b2f((unsigned short)xa2[q]) - b2f((unsigned short)ra2[q])) * w0
                           + (b2f((unsigned short)xb2[q]) - b2f((unsigned short)rb2[q])) * w1;
                a[24 + q] += (b2f((unsigned short)xa3[q]) - b2f((unsigned short)ra3[q])) * w0
                           + (b2f((unsigned short)xb3[q]) - b2f((unsigned short)rb3[q])) * w1;
            }
        }
        // dump bf16 tile, slot XOR-swizzled by row
        bf16x8* dA = (bf16x8*)sA;
#pragma unroll
        for (int j = 0; j < 4; ++j) {
            int slot = c * 4 + j;
            bf16x8 ov;
#pragma unroll
            for (int q = 0; q < 8; ++q) ov[q] = (short)f2b(a[j * 8 + q]);
            dA[nl * 16 + (slot ^ (nl & 15))] = ov;
        }
    } else {
        // ---- phase 1 (rel): stage rel rows into LDS, swizzled ----
        int rbase = ((int)blockIdx.x - nblk) * DD;
        const bf16x8* Rin = (const bf16x8*)relb;
        bf16x8* dA = (bf16x8*)sA;
        for (int i = tid; i < DD * 16; i += 512) {
            int row = i >> 4, slot = i & 15;
            int grow = rbase + row;
            bf16x8 v = {};
            if (grow < R) v = Rin[(size_t)grow * 16 + slot];
            dA[row * 16 + (slot ^ (row & 15))] = v;
        }
    }
    __syncthreads();

    // ---- phase 2: GEMM. out = A@W (+ X@Wself for node blocks) ----
    int w = tid >> 6, l = tid & 63;
    int lr = l & 15, lk = l >> 4;
    int trow = w * 16 + lr;                     // row within 128-tile
    const bf16x8* sA8 = (const bf16x8*)sA;
    const unsigned short* B0 = isrel ? wtR : wtA;

    f32x4 acc[8];
#pragma unroll
    for (int ct = 0; ct < 8; ++ct) acc[ct] = (f32x4){0.f, 0.f, 0.f, 0.f};

    if (!isrel) {
        int row = blockIdx.x * DD + trow;
        bool v = row < N;
#pragma unroll
        for (int kb = 0; kb < 4; ++kb) {
            int koff = kb * 32 + lk * 8;
            bf16x8 afr = sA8[trow * 16 + ((kb * 4 + lk) ^ lr)];
            bf16x8 xfr = {};
            if (v) xfr = *(const bf16x8*)(gx + (size_t)row * DD + koff);
#pragma unroll
            for (int ct = 0; ct < 8; ++ct) {
                int wrow = ct * 16 + lr;
                bf16x8 bw = *(const bf16x8*)(B0 + wrow * DD + koff);
                bf16x8 bs = *(const bf16x8*)(wtX + wrow * DD + koff);
                acc[ct] = __builtin_amdgcn_mfma_f32_16x16x32_bf16(bw, afr, acc[ct], 0, 0, 0);
                acc[ct] = __builtin_amdgcn_mfma_f32_16x16x32_bf16(bs, xfr, acc[ct], 0, 0, 0);
            }
        }
        if (v) {
#pragma unroll
            for (int ct = 0; ct < 8; ++ct) {
                f32x4 vv = acc[ct];
                if (relu) {
                    vv[0] = fmaxf(vv[0], 0.f); vv[1] = fmaxf(vv[1], 0.f);
                    vv[2] = fmaxf(vv[2], 0.f); vv[3] = fmaxf(vv[3], 0.f);
                }
                int cb = ct * 16 + lk * 4;
                if (outf) *(f32x4*)(outf + (size_t)row * DD + cb) = vv;
                if (outb) {
                    *(ushort4*)(outb + (size_t)row * DD + cb) =
                        make_ushort4(f2b(vv[0]), f2b(vv[1]), f2b(vv[2]), f2b(vv[3]));
                }
            }
        }
    } else {
        int rbase = ((int)blockIdx.x - nblk) * DD;
        int row = rbase + trow;
        bool v = row < R;
#pragma unroll
        for (int kb = 0; kb < 4; ++kb) {
            int koff = kb * 32 + lk * 8;
            bf16x8 afr = sA8[trow * 16 + ((kb * 4 + lk) ^ lr)];
#pragma unroll
            for (int ct = 0; ct < 8; ++ct) {
                int wrow = ct * 16 + lr;
                bf16x8 bw = *(const bf16x8*)(B0 + wrow * DD + koff);
                acc[ct] = __builtin_amdgcn_mfma_f32_16x16x32_bf16(bw, afr, acc[ct], 0, 0, 0);
            }
        }
        if (v) {
#pragma unroll
            for (int ct = 0; ct < 8; ++ct) {
                f32x4 vv = acc[ct];
                if (relu) {
                    vv[0] = fmaxf(vv[0], 0.f); vv[1] = fmaxf(vv[1], 0.f);
                    vv[2] = fmaxf(vv[2], 0.f); vv[3] = fmaxf(vv[3], 0.f);
                }
                int cb = ct * 16 + lk * 4;
                if (reloutf) *(f32x4*)(reloutf + (size_t)row * DD + cb) = vv;
                if (reloutb) {
                    *(ushort4*)(reloutb + (size_t)row * DD + cb) =
                        make_ushort4(f2b(vv[0]), f2b(vv[1]), f2b(vv[2]), f2b(vv[3]));
                }
            }
        }
    }
}

// ---------------- launcher ----------------

extern "C" void kernel_launch(void* const* d_in, const int* in_sizes, int n_in,
                              void* d_out, int out_size, void* d_ws, size_t ws_size,
                              hipStream_t stream) {
    const int*   ei  = (const int*)d_in[0];
    const int*   ety = (const int*)d_in[1];
    const float* ew  = (const float*)d_in[2];
    const float* x0  = (const float*)d_in[3];
    const float* r0  = (const float*)d_in[4];
    const float* W0  = (const float*)d_in[5];
    const float* Ws0 = (const float*)d_in[6];
    const float* Wr0 = (const float*)d_in[7];
    const float* W1  = (const float*)d_in[8];
    const float* Ws1 = (const float*)d_in[9];
    const float* Wr1 = (const float*)d_in[10];

    const int E = in_sizes[1];
    const int N = in_sizes[3] / DD;
    const int R = in_sizes[4] / DD;

    float* out_x = (float*)d_out;                 // [N,128] f32
    float* out_r = out_x + (size_t)N * DD;        // [R,128] f32

    char* w = (char*)d_ws;
    size_t off = 0;
    auto alloc = [&](size_t bytes) {
        void* p = w + off;
        off += (bytes + 255) & ~(size_t)255;
        return p;
    };
    unsigned short* xb    = (unsigned short*)alloc((size_t)N * DD * 2);  // 25.6 MB
    unsigned short* x1b   = (unsigned short*)alloc((size_t)N * DD * 2);  // 25.6 MB
    unsigned short* r0b   = (unsigned short*)alloc((size_t)R * DD * 2);
    unsigned short* rel1b = (unsigned short*)alloc((size_t)R * DD * 2);
    unsigned short* wt0a  = (unsigned short*)alloc((size_t)DD * DD * 2);
    unsigned short* wt0s  = (unsigned short*)alloc((size_t)DD * DD * 2);
    unsigned short* wt1a  = (unsigned short*)alloc((size_t)DD * DD * 2);
    unsigned short* wt1s  = (unsigned short*)alloc((size_t)DD * DD * 2);
    unsigned short* wtr0  = (unsigned short*)alloc((size_t)DD * DD * 2);
    unsigned short* wtr1  = (unsigned short*)alloc((size_t)DD * DD * 2);
    int*   startv = (int*)alloc((size_t)(N + 1) * 4);
    int*   cursor = (int*)alloc((size_t)N * 4);
    int*   bsum   = (int*)alloc(512 * 4);
    uint2* csre   = (uint2*)alloc((size_t)E * 8);
    (void)ws_size; (void)n_in; (void)out_size;

    int ebl = (E + 255) / 256;
    int nb  = (N + 255) / 256;
    int n4x = N * 32, n4r = R * 32;
    int bx = (n4x + 255) / 256, br = (n4r + 255) / 256;

    // --- CSR build ---
    int* cnt = cursor;
    hipMemsetAsync(cnt, 0, (size_t)N * 4, stream);
    hist_kernel<<<ebl, 256, 0, stream>>>(ei, cnt, E);
    scan1_kernel<<<nb, 256, 0, stream>>>(cnt, startv, bsum, N);
    scan2_kernel<<<1, 512, 0, stream>>>(bsum, nb);
    scan3_kernel<<<(N + 1 + 255) / 256, 256, 0, stream>>>(startv, cursor, bsum, N, E);

    // --- fused CSR scatter + conversions ---
    fill_conv_kernel<<<ebl + bx + br + 384, 256, 0, stream>>>(
        ei, ety, ew, cursor, csre, E, ebl,
        x0, xb, bx, n4x, r0, r0b, br, n4r,
        W0, Ws0, W1, Ws1, Wr0, Wr1,
        wt0a, wt0s, wt1a, wt1s, wtr0, wtr1);

    int nblk = (N + DD - 1) / DD;
    int rblk = (R + DD - 1) / DD;

    // --- layer 0: x1b = relu(agg@W0 + x0@Wself0); rel1b = relu(r0@Wrel0) ---
    fused_layer_kernel<<<nblk + rblk, 512, 0, stream>>>(
        xb, r0b, wt0a, wt0s, wtr0, startv, csre,
        nullptr, x1b, nullptr, rel1b, N, R, 1, nblk);

    // --- layer 1: out_x = agg@W1 + x1@Wself1; out_r = rel1@Wrel1 ---
    fused_layer_kernel<<<nblk + rblk, 512, 0, stream>>>(
        x1b, rel1b, wt1a, wt1s, wtr1, startv, csre,
        out_x, nullptr, out_r, nullptr, N, R, 0, nblk);
}

// Round 9
// 208.592 us; speedup vs baseline: 1.4220x; 1.4220x over previous
//
#include <hip/hip_runtime.h>

#define DD 128

typedef __attribute__((ext_vector_type(8))) short bf16x8;
typedef __attribute__((ext_vector_type(4))) float f32x4;

__device__ __forceinline__ float b2f(unsigned short u) {
    return __uint_as_float(((unsigned)u) << 16);
}
__device__ __forceinline__ unsigned short f2b(float f) {
    unsigned u = __float_as_uint(f);
    unsigned r = (u + 0x7FFFu + ((u >> 16) & 1u)) >> 16;
    return (unsigned short)r;
}

// ---------------- CSR build ----------------

__global__ __launch_bounds__(256) void scan1_kernel(const int* __restrict__ cnt,
                                                    int* __restrict__ startv,
                                                    int* __restrict__ bsum, int n) {
    int i = blockIdx.x * 256 + threadIdx.x;
    int v = (i < n) ? cnt[i] : 0;
    int lane = threadIdx.x & 63, wid = threadIdx.x >> 6;
    int incl = v;
#pragma unroll
    for (int o = 1; o < 64; o <<= 1) {
        int t = __shfl_up(incl, o);
        if (lane >= o) incl += t;
    }
    __shared__ int wsum[4];
    __shared__ int wpre[4];
    if (lane == 63) wsum[wid] = incl;
    __syncthreads();
    if (threadIdx.x == 0) {
        int s = 0;
        for (int w2 = 0; w2 < 4; ++w2) { wpre[w2] = s; s += wsum[w2]; }
        bsum[blockIdx.x] = s;
    }
    __syncthreads();
    if (i < n) startv[i] = incl - v + wpre[wid];
}

__global__ __launch_bounds__(512) void scan2_kernel(int* bsum, int nb) {
    int i = threadIdx.x;
    int v = (i < nb) ? bsum[i] : 0;
    int lane = threadIdx.x & 63, wid = threadIdx.x >> 6;
    int incl = v;
#pragma unroll
    for (int o = 1; o < 64; o <<= 1) {
        int t = __shfl_up(incl, o);
        if (lane >= o) incl += t;
    }
    __shared__ int wsum[8];
    __shared__ int wpre[8];
    if (lane == 63) wsum[wid] = incl;
    __syncthreads();
    if (threadIdx.x == 0) {
        int s = 0;
        for (int w2 = 0; w2 < 8; ++w2) { wpre[w2] = s; s += wsum[w2]; }
    }
    __syncthreads();
    if (i < nb) bsum[i] = incl - v + wpre[wid];
}

__global__ __launch_bounds__(256) void scan3_kernel(int* startv, int* cursor,
                                                    const int* __restrict__ bsum,
                                                    int n, int E) {
    int i = blockIdx.x * 256 + threadIdx.x;
    if (i < n) {
        int s = startv[i] + bsum[i >> 8];
        startv[i] = s;
        cursor[i] = s;
    } else if (i == n) {
        startv[n] = E;
    }
}

// fill: 2 edges/thread -> 2 independent atomic+scatter chains (latency-bound)
__global__ __launch_bounds__(256) void fill_kernel(const int* __restrict__ ei,
                                                   const int* __restrict__ ety,
                                                   const float* __restrict__ ew,
                                                   int* cursor,
                                                   uint2* __restrict__ csre, int E) {
    int e0 = blockIdx.x * 512 + threadIdx.x;
    int e1 = e0 + 256;
    if (e0 < E) {
        int dst = ei[E + e0];
        int p = atomicAdd(&cursor[dst], 1);
        uint2 rec;
        rec.x = ((unsigned)ei[e0]) | (((unsigned)ety[e0]) << 20);
        rec.y = __float_as_uint(ew[e0]);
        __builtin_nontemporal_store(*(unsigned long long*)&rec,
                                    (unsigned long long*)&csre[p]);
    }
    if (e1 < E) {
        int dst = ei[E + e1];
        int p = atomicAdd(&cursor[dst], 1);
        uint2 rec;
        rec.x = ((unsigned)ei[e1]) | (((unsigned)ety[e1]) << 20);
        rec.y = __float_as_uint(ew[e1]);
        __builtin_nontemporal_store(*(unsigned long long*)&rec,
                                    (unsigned long long*)&csre[p]);
    }
}

// ---------------- merged conversions + histogram ----------------
// blocks: [0,bx) x0->xb ; [bx,bx+br) r0->r0b ; [.., +384) 6 W transposes ; rest: hist

__global__ __launch_bounds__(256) void prep_hist_kernel(
    const float* __restrict__ x0, unsigned short* __restrict__ xb, int bx, int n4x,
    const float* __restrict__ r0, unsigned short* __restrict__ r0b, int br, int n4r,
    const float* __restrict__ W0, const float* __restrict__ Ws0,
    const float* __restrict__ W1, const float* __restrict__ Ws1,
    const float* __restrict__ Wr0, const float* __restrict__ Wr1,
    unsigned short* __restrict__ wt0a, unsigned short* __restrict__ wt0s,
    unsigned short* __restrict__ wt1a, unsigned short* __restrict__ wt1s,
    unsigned short* __restrict__ wtr0, unsigned short* __restrict__ wtr1,
    const int* __restrict__ ei, int* __restrict__ cnt, int E) {
    int bid = blockIdx.x;
    if (bid < bx) {
        int i = bid * 256 + threadIdx.x;
        if (i < n4x) {
            float4 v = ((const float4*)x0)[i];
            ((ushort4*)xb)[i] = make_ushort4(f2b(v.x), f2b(v.y), f2b(v.z), f2b(v.w));
        }
        return;
    }
    bid -= bx;
    if (bid < br) {
        int i = bid * 256 + threadIdx.x;
        if (i < n4r) {
            float4 v = ((const float4*)r0)[i];
            ((ushort4*)r0b)[i] = make_ushort4(f2b(v.x), f2b(v.y), f2b(v.z), f2b(v.w));
        }
        return;
    }
    bid -= br;
    if (bid < 384) {
        int which = bid >> 6;
        int i = (bid & 63) * 256 + threadIdx.x;  // 0..16383
        int cc = i >> 7, k = i & 127;
        const float* Wsel = which == 0 ? W0 : which == 1 ? Ws0 : which == 2 ? W1
                          : which == 3 ? Ws1 : which == 4 ? Wr0 : Wr1;
        unsigned short* Osel = which == 0 ? wt0a : which == 1 ? wt0s : which == 2 ? wt1a
                             : which == 3 ? wt1s : which == 4 ? wtr0 : wtr1;
        Osel[i] = f2b(Wsel[k * DD + cc]);      // Wt[c][k] = W[k][c]
        return;
    }
    bid -= 384;
    int e = bid * 256 + threadIdx.x;
    if (e < E) atomicAdd(&cnt[ei[E + e]], 1);
}

// ---------------- aggregation: aggb[n] = bf16( sum_e w*(x[src]-rel[t]) ) ----------------
// 16 lanes/slot, each slot owns 2 nodes (n, n+16); 2-edge unroll per node
// -> 4 independent gather chains per lane, 16 per wave.

__global__ __launch_bounds__(256) void aggregate_kernel(
    const unsigned short* __restrict__ xb, const unsigned short* __restrict__ relb,
    const int* __restrict__ startv, const uint2* __restrict__ csre,
    unsigned short* __restrict__ aggb, int n) {
    int slot = threadIdx.x >> 4;      // 0..15
    int c = threadIdx.x & 15;         // 16B chunk within the 256B bf16 row
    int n0 = blockIdx.x * 32 + slot;
    int n1 = n0 + 16;
    int i0 = 0, e0 = 0, i1 = 0, e1 = 0;
    if (n0 < n) { i0 = startv[n0]; e0 = startv[n0 + 1]; }
    if (n1 < n) { i1 = startv[n1]; e1 = startv[n1 + 1]; }
    const bf16x8* X = (const bf16x8*)xb;
    const bf16x8* Rl = (const bf16x8*)relb;
    float p0[8], q0[8], p1[8], q1[8];
#pragma unroll
    for (int j = 0; j < 8; ++j) { p0[j] = 0.f; q0[j] = 0.f; p1[j] = 0.f; q1[j] = 0.f; }
    while (i0 < e0 || i1 < e1) {
        bool v00 = i0 < e0, v01 = i0 + 1 < e0;
        bool v10 = i1 < e1, v11 = i1 + 1 < e1;
        uint2 c00 = csre[v00 ? i0 : 0];
        uint2 c01 = csre[v01 ? i0 + 1 : 0];
        uint2 c10 = csre[v10 ? i1 : 0];
        uint2 c11 = csre[v11 ? i1 + 1 : 0];
        float w00 = v00 ? __uint_as_float(c00.y) : 0.f;
        float w01 = v01 ? __uint_as_float(c01.y) : 0.f;
        float w10 = v10 ? __uint_as_float(c10.y) : 0.f;
        float w11 = v11 ? __uint_as_float(c11.y) : 0.f;
        bf16x8 x00 = X[(size_t)(c00.x & 0xFFFFFu) * 16 + c];
        bf16x8 x01 = X[(size_t)(c01.x & 0xFFFFFu) * 16 + c];
        bf16x8 x10 = X[(size_t)(c10.x & 0xFFFFFu) * 16 + c];
        bf16x8 x11 = X[(size_t)(c11.x & 0xFFFFFu) * 16 + c];
        bf16x8 r00 = Rl[(c00.x >> 20) * 16 + c];
        bf16x8 r01 = Rl[(c01.x >> 20) * 16 + c];
        bf16x8 r10 = Rl[(c10.x >> 20) * 16 + c];
        bf16x8 r11 = Rl[(c11.x >> 20) * 16 + c];
#pragma unroll
        for (int j = 0; j < 8; ++j) {
            p0[j] += (b2f((unsigned short)x00[j]) - b2f((unsigned short)r00[j])) * w00;
            q0[j] += (b2f((unsigned short)x01[j]) - b2f((unsigned short)r01[j])) * w01;
            p1[j] += (b2f((unsigned short)x10[j]) - b2f((unsigned short)r10[j])) * w10;
            q1[j] += (b2f((unsigned short)x11[j]) - b2f((unsigned short)r11[j])) * w11;
        }
        i0 = min(i0 + 2, e0);
        i1 = min(i1 + 2, e1);
    }
    if (n0 < n) {
        bf16x8 ov;
#pragma unroll
        for (int j = 0; j < 8; ++j) ov[j] = (short)f2b(p0[j] + q0[j]);
        ((bf16x8*)aggb)[(size_t)n0 * 16 + c] = ov;
    }
    if (n1 < n) {
        bf16x8 ov;
#pragma unroll
        for (int j = 0; j < 8; ++j) ov[j] = (short)f2b(p1[j] + q1[j]);
        ((bf16x8*)aggb)[(size_t)n1 * 16 + c] = ov;
    }
}

// ---------------- fused dual GEMM via MFMA (swapped operands, 512 threads) ----------
// node blocks [0,gbl): out = A@W + X@Wself. rel blocks [gbl, gbl+rblk):
// relout = act(relsrc@Wrel) -- same MFMA path, X-term skipped, wtR in sW[0].
// 8 waves/block, 16 rows/wave. C^T layout -> one f32x4/bf16x4 store per tile.

__global__ __launch_bounds__(512, 4) void mfma_dual_gemm_kernel(
    const unsigned short* __restrict__ A, const unsigned short* __restrict__ X,
    const unsigned short* __restrict__ WtA, const unsigned short* __restrict__ WtX,
    float* __restrict__ outf, unsigned short* __restrict__ outb,
    int nrows, int relu,
    const unsigned short* __restrict__ relsrc, const unsigned short* __restrict__ WtR,
    float* __restrict__ reloutf, unsigned short* __restrict__ reloutb,
    int R, int gbl) {
    __shared__ unsigned short sW[2][DD * DD];   // 64 KB
    bool isrel = (int)blockIdx.x >= gbl;
    const unsigned short* srcA = isrel ? WtR : WtA;
    for (int i = threadIdx.x; i < 2048; i += 512) {
        int row = i >> 4, slot = i & 15;
        int so = (slot ^ (row & 15)) * 8;
        *(float4*)&sW[0][row * DD + so] = ((const float4*)srcA)[i];
        *(float4*)&sW[1][row * DD + so] = ((const float4*)WtX)[i];
    }
    __syncthreads();
    int w = threadIdx.x >> 6, l = threadIdx.x & 63;
    int lr = l & 15, lk = l >> 4;

    f32x4 acc[8];
#pragma unroll
    for (int ct = 0; ct < 8; ++ct) acc[ct] = (f32x4){0.f, 0.f, 0.f, 0.f};

    if (!isrel) {
        int row = blockIdx.x * 128 + w * 16 + lr;
        bool v = row < nrows;
#pragma unroll
        for (int kb = 0; kb < 4; ++kb) {
            int koff = kb * 32 + lk * 8;
            bf16x8 a = {}, x = {};
            if (v) {
                a = *(const bf16x8*)(A + (size_t)row * DD + koff);
                x = *(const bf16x8*)(X + (size_t)row * DD + koff);
            }
#pragma unroll
            for (int ct = 0; ct < 8; ++ct) {
                int wrow = ct * 16 + lr;
                int slot = kb * 4 + lk;
                int so = (slot ^ (wrow & 15)) * 8;
                bf16x8 bw = *(const bf16x8*)&sW[0][wrow * DD + so];
                bf16x8 bs = *(const bf16x8*)&sW[1][wrow * DD + so];
                acc[ct] = __builtin_amdgcn_mfma_f32_16x16x32_bf16(bw, a, acc[ct], 0, 0, 0);
                acc[ct] = __builtin_amdgcn_mfma_f32_16x16x32_bf16(bs, x, acc[ct], 0, 0, 0);
            }
        }
        if (v) {
#pragma unroll
            for (int ct = 0; ct < 8; ++ct) {
                f32x4 vv = acc[ct];
                if (relu) {
                    vv[0] = fmaxf(vv[0], 0.f); vv[1] = fmaxf(vv[1], 0.f);
                    vv[2] = fmaxf(vv[2], 0.f); vv[3] = fmaxf(vv[3], 0.f);
                }
                int cb = ct * 16 + lk * 4;
                if (outf) *(f32x4*)(outf + (size_t)row * DD + cb) = vv;
                if (outb) {
                    *(ushort4*)(outb + (size_t)row * DD + cb) =
                        make_ushort4(f2b(vv[0]), f2b(vv[1]), f2b(vv[2]), f2b(vv[3]));
                }
            }
        }
    } else {
        int row = ((int)blockIdx.x - gbl) * 128 + w * 16 + lr;
        bool v = row < R;
#pragma unroll
        for (int kb = 0; kb < 4; ++kb) {
            int koff = kb * 32 + lk * 8;
            bf16x8 a = {};
            if (v) a = *(const bf16x8*)(relsrc + (size_t)row * DD + koff);
#pragma unroll
            for (int ct = 0; ct < 8; ++ct) {
                int wrow = ct * 16 + lr;
                int slot = kb * 4 + lk;
                int so = (slot ^ (wrow & 15)) * 8;
                bf16x8 bw = *(const bf16x8*)&sW[0][wrow * DD + so];
                acc[ct] = __builtin_amdgcn_mfma_f32_16x16x32_bf16(bw, a, acc[ct], 0, 0, 0);
            }
        }
        if (v) {
#pragma unroll
            for (int ct = 0; ct < 8; ++ct) {
                f32x4 vv = acc[ct];
                if (relu) {
                    vv[0] = fmaxf(vv[0], 0.f); vv[1] = fmaxf(vv[1], 0.f);
                    vv[2] = fmaxf(vv[2], 0.f); vv[3] = fmaxf(vv[3], 0.f);
                }
                int cb = ct * 16 + lk * 4;
                if (reloutf) *(f32x4*)(reloutf + (size_t)row * DD + cb) = vv;
                if (reloutb) {
                    *(ushort4*)(reloutb + (size_t)row * DD + cb) =
                        make_ushort4(f2b(vv[0]), f2b(vv[1]), f2b(vv[2]), f2b(vv[3]));
                }
            }
        }
    }
}

// ---------------- launcher ----------------

extern "C" void kernel_launch(void* const* d_in, const int* in_sizes, int n_in,
                              void* d_out, int out_size, void* d_ws, size_t ws_size,
                              hipStream_t stream) {
    const int*   ei  = (const int*)d_in[0];
    const int*   ety = (const int*)d_in[1];
    const float* ew  = (const float*)d_in[2];
    const float* x0  = (const float*)d_in[3];
    const float* r0  = (const float*)d_in[4];
    const float* W0  = (const float*)d_in[5];
    const float* Ws0 = (const float*)d_in[6];
    const float* Wr0 = (const float*)d_in[7];
    const float* W1  = (const float*)d_in[8];
    const float* Ws1 = (const float*)d_in[9];
    const float* Wr1 = (const float*)d_in[10];

    const int E = in_sizes[1];
    const int N = in_sizes[3] / DD;
    const int R = in_sizes[4] / DD;

    float* out_x = (float*)d_out;                 // [N,128] f32
    float* out_r = out_x + (size_t)N * DD;        // [R,128] f32

    char* w = (char*)d_ws;
    size_t off = 0;
    auto alloc = [&](size_t bytes) {
        void* p = w + off;
        off += (bytes + 255) & ~(size_t)255;
        return p;
    };
    unsigned short* aggb  = (unsigned short*)alloc((size_t)N * DD * 2);  // 25.6 MB
    unsigned short* xb    = (unsigned short*)alloc((size_t)N * DD * 2);  // 25.6 MB
    unsigned short* r0b   = (unsigned short*)alloc((size_t)R * DD * 2);
    unsigned short* rel1b = (unsigned short*)alloc((size_t)R * DD * 2);
    unsigned short* wt0a  = (unsigned short*)alloc((size_t)DD * DD * 2);
    unsigned short* wt0s  = (unsigned short*)alloc((size_t)DD * DD * 2);
    unsigned short* wt1a  = (unsigned short*)alloc((size_t)DD * DD * 2);
    unsigned short* wt1s  = (unsigned short*)alloc((size_t)DD * DD * 2);
    unsigned short* wtr0  = (unsigned short*)alloc((size_t)DD * DD * 2);
    unsigned short* wtr1  = (unsigned short*)alloc((size_t)DD * DD * 2);
    int*   startv = (int*)alloc((size_t)(N + 1) * 4);
    int*   cursor = (int*)alloc((size_t)N * 4);
    int*   bsum   = (int*)alloc(512 * 4);
    uint2* csre   = (uint2*)alloc((size_t)E * 8);
    (void)ws_size; (void)n_in; (void)out_size;

    int ebl = (E + 255) / 256;
    int nb  = (N + 255) / 256;
    int n4x = N * 32, n4r = R * 32;
    int bx = (n4x + 255) / 256, br = (n4r + 255) / 256;

    // --- conversions + histogram (fused) ---
    int* cnt = cursor;
    hipMemsetAsync(cnt, 0, (size_t)N * 4, stream);
    prep_hist_kernel<<<bx + br + 384 + ebl, 256, 0, stream>>>(
        x0, xb, bx, n4x, r0, r0b, br, n4r,
        W0, Ws0, W1, Ws1, Wr0, Wr1,
        wt0a, wt0s, wt1a, wt1s, wtr0, wtr1, ei, cnt, E);
    scan1_kernel<<<nb, 256, 0, stream>>>(cnt, startv, bsum, N);
    scan2_kernel<<<1, 512, 0, stream>>>(bsum, nb);
    scan3_kernel<<<(N + 1 + 255) / 256, 256, 0, stream>>>(startv, cursor, bsum, N, E);
    fill_kernel<<<(E + 511) / 512, 256, 0, stream>>>(ei, ety, ew, cursor, csre, E);

    int abl = (N + 31) / 32;
    int gbl = (N + 127) / 128;
    int rblk = (R + 127) / 128;

    // --- layer 0: xb <- relu(agg@W0 + x0@Wself0) in place; rel1b = relu(r0@Wrel0) ---
    aggregate_kernel<<<abl, 256, 0, stream>>>(xb, r0b, startv, csre, aggb, N);
    mfma_dual_gemm_kernel<<<gbl + rblk, 512, 0, stream>>>(
        aggb, xb, wt0a, wt0s, nullptr, xb, N, 1,
        r0b, wtr0, nullptr, rel1b, R, gbl);

    // --- layer 1: out_x = agg@W1 + x1@Wself1; out_r = rel1@Wrel1 ---
    aggregate_kernel<<<abl, 256, 0, stream>>>(xb, rel1b, startv, csre, aggb, N);
    mfma_dual_gemm_kernel<<<gbl + rblk, 512, 0, stream>>>(
        aggb, xb, wt1a, wt1s, out_x, nullptr, N, 0,
        rel1b, wtr1, out_r, nullptr, R, gbl);
}